// Round 1
// baseline (1723.393 us; speedup 1.0000x reference)
//
#include <hip/hip_runtime.h>
#include <math.h>

#define NPTS 32768
#define DIM  256
#define KCB  4096
#define NQ   (NPTS*DIM)          // 8388608

#define EPSN   1e-12f
#define MARGIN 1e-4f

// GEMM tile config (phase 1)
#define BM 128
#define BN 128
#define BD 64

// ws layout (byte offsets), total ~4.75 MB
#define WS_ENORM 0                                   // KCB*DIM f32 (4 MB)
#define WS_SUME  (4194304)                           // KCB f32
#define WS_XINV  (4194304+16384)                     // NPTS f32
#define WS_SUMX  (4194304+16384+131072)              // NPTS f32
#define WS_IDX   (4194304+16384+262144)              // NPTS i32
#define WS_RCNT  (4194304+16384+393216)              // 1 i32 (+pad)
#define WS_RROWS (4194304+16384+393216+16)           // NPTS i32
#define WS_LOSSP (4194304+16384+393216+16+131072)    // 2048 f32

__global__ void k_init(int* rcnt) {
    if (threadIdx.x == 0) *rcnt = 0;
}

// one wave per row: inv-norm + sum of squares of normalized row
__global__ __launch_bounds__(256) void k_norm_x(const float* __restrict__ x,
                                                float* __restrict__ xinv,
                                                float* __restrict__ sumx) {
    int wid = threadIdx.x >> 6, lane = threadIdx.x & 63;
    int row = blockIdx.x * 4 + wid;
    float4 v = ((const float4*)x)[row * (DIM/4) + lane];
    float s = v.x*v.x + v.y*v.y + v.z*v.z + v.w*v.w;
    #pragma unroll
    for (int o = 32; o; o >>= 1) s += __shfl_xor(s, o);
    float den = fmaxf(sqrtf(s), EPSN);
    float inv = 1.0f / den;
    float4 xn = make_float4(v.x*inv, v.y*inv, v.z*inv, v.w*inv);
    float s2 = xn.x*xn.x + xn.y*xn.y + xn.z*xn.z + xn.w*xn.w;
    #pragma unroll
    for (int o = 32; o; o >>= 1) s2 += __shfl_xor(s2, o);
    if (lane == 0) { xinv[row] = inv; sumx[row] = s2; }
}

// one wave per codebook row: write normalized row + its sum of squares
__global__ __launch_bounds__(256) void k_norm_e(const float* __restrict__ e,
                                                float* __restrict__ en,
                                                float* __restrict__ sume) {
    int wid = threadIdx.x >> 6, lane = threadIdx.x & 63;
    int row = blockIdx.x * 4 + wid;
    float4 v = ((const float4*)e)[row * (DIM/4) + lane];
    float s = v.x*v.x + v.y*v.y + v.z*v.z + v.w*v.w;
    #pragma unroll
    for (int o = 32; o; o >>= 1) s += __shfl_xor(s, o);
    float den = fmaxf(sqrtf(s), EPSN);
    float inv = 1.0f / den;
    float4 xn = make_float4(v.x*inv, v.y*inv, v.z*inv, v.w*inv);
    ((float4*)en)[row * (DIM/4) + lane] = xn;
    float s2 = xn.x*xn.x + xn.y*xn.y + xn.z*xn.z + xn.w*xn.w;
    #pragma unroll
    for (int o = 32; o; o >>= 1) s2 += __shfl_xor(s2, o);
    if (lane == 0) sume[row] = s2;
}

// phase 1: fp32 GEMM with fused top-2 argmin epilogue.
// block = 256 threads (16x16), micro-tile 8x8, BM=128 rows x all K.
__global__ __launch_bounds__(256) void k_phase1(const float* __restrict__ x,
                                                const float* __restrict__ en,
                                                const float* __restrict__ xinv,
                                                const float* __restrict__ sumx,
                                                const float* __restrict__ sume,
                                                int* __restrict__ idx,
                                                int* __restrict__ rcnt,
                                                int* __restrict__ rrows) {
    __shared__ float As[BD][BM + 4];   // d-major: As[d][row]
    __shared__ float Bs[BD][BN + 4];   // d-major: Bs[d][col]
    __shared__ float sxs[BM];

    int tid = threadIdx.x;
    int tx = tid & 15, ty = tid >> 4;
    int rowbase = blockIdx.x * BM;

    if (tid < BM) sxs[tid] = sumx[rowbase + tid];

    // staging mapping: coalesced global float4 loads
    int ld4 = tid & 15;     // which float4 within the 64-float d-chunk
    int rgrp = tid >> 4;    // row/col group 0..15

    float xiv8[8];
    #pragma unroll
    for (int s = 0; s < 8; s++) xiv8[s] = xinv[rowbase + rgrp + 16*s];

    float d1[8], d2[8]; int k1[8];
    #pragma unroll
    for (int i = 0; i < 8; i++) { d1[i] = INFINITY; d2[i] = INFINITY; k1[i] = 0; }

    const float4* x4 = (const float4*)x;
    const float4* en4 = (const float4*)en;

    for (int kt = 0; kt < KCB / BN; ++kt) {
        float acc[8][8];
        #pragma unroll
        for (int i = 0; i < 8; i++)
            #pragma unroll
            for (int j = 0; j < 8; j++) acc[i][j] = 0.f;

        for (int dc = 0; dc < DIM / BD; ++dc) {
            __syncthreads();
            // stage A (normalize on the fly)
            #pragma unroll
            for (int s = 0; s < 8; s++) {
                int row = rgrp + 16*s;
                float4 f = x4[(rowbase + row) * (DIM/4) + dc * (BD/4) + ld4];
                int ld = ld4 * 4;
                float xv = xiv8[s];
                As[ld+0][row] = f.x * xv;
                As[ld+1][row] = f.y * xv;
                As[ld+2][row] = f.z * xv;
                As[ld+3][row] = f.w * xv;
            }
            // stage B (already normalized in ws)
            #pragma unroll
            for (int s = 0; s < 8; s++) {
                int col = rgrp + 16*s;
                float4 f = en4[(kt * BN + col) * (DIM/4) + dc * (BD/4) + ld4];
                int ld = ld4 * 4;
                Bs[ld+0][col] = f.x;
                Bs[ld+1][col] = f.y;
                Bs[ld+2][col] = f.z;
                Bs[ld+3][col] = f.w;
            }
            __syncthreads();
            // compute: outer products over the d-chunk
            #pragma unroll 4
            for (int dd = 0; dd < BD; ++dd) {
                float4 a0 = *(const float4*)&As[dd][ty * 8];
                float4 a1 = *(const float4*)&As[dd][ty * 8 + 4];
                float4 b0 = *(const float4*)&Bs[dd][tx * 8];
                float4 b1 = *(const float4*)&Bs[dd][tx * 8 + 4];
                float ar[8] = {a0.x,a0.y,a0.z,a0.w,a1.x,a1.y,a1.z,a1.w};
                float br[8] = {b0.x,b0.y,b0.z,b0.w,b1.x,b1.y,b1.z,b1.w};
                #pragma unroll
                for (int i = 0; i < 8; i++)
                    #pragma unroll
                    for (int j = 0; j < 8; j++)
                        acc[i][j] = fmaf(ar[i], br[j], acc[i][j]);
            }
        }
        // epilogue: distances + top-2 update (k ascending -> first-min tiebreak)
        #pragma unroll
        for (int i = 0; i < 8; i++) {
            float sx = sxs[ty * 8 + i];
            #pragma unroll
            for (int j = 0; j < 8; j++) {
                int k = kt * BN + tx * 8 + j;
                float dist = (sx + sume[k]) - 2.0f * acc[i][j];
                if (dist < d1[i]) { d2[i] = d1[i]; d1[i] = dist; k1[i] = k; }
                else if (dist < d2[i]) { d2[i] = dist; }
            }
        }
    }

    // reduce top-2 across the 16 tx lanes (within wave)
    #pragma unroll
    for (int i = 0; i < 8; i++) {
        float a1v = d1[i], a2v = d2[i]; int ak = k1[i];
        #pragma unroll
        for (int off = 1; off < 16; off <<= 1) {
            float o1 = __shfl_xor(a1v, off);
            float o2 = __shfl_xor(a2v, off);
            int   ok = __shfl_xor(ak,  off);
            bool take = (o1 < a1v) || (o1 == a1v && ok < ak);
            float loser = take ? a1v : o1;
            float wins2 = take ? o2 : a2v;
            a1v = take ? o1 : a1v;
            ak  = take ? ok : ak;
            a2v = fminf(loser, wins2);
        }
        if (tx == 0) {
            int grow = rowbase + ty * 8 + i;
            idx[grow] = ak;
            if (a2v - a1v < MARGIN) {
                int p = atomicAdd(rcnt, 1);
                rrows[p] = grow;
            }
        }
    }
}

// phase 2: f64 rescue for near-tie rows — exact rescore against all K codes
__global__ __launch_bounds__(256) void k_phase2(const float* __restrict__ x,
                                                const float* __restrict__ en,
                                                const float* __restrict__ xinv,
                                                const float* __restrict__ sumx,
                                                const float* __restrict__ sume,
                                                int* __restrict__ idx,
                                                const int* __restrict__ rcnt,
                                                const int* __restrict__ rrows) {
    __shared__ __align__(16) float xs[DIM];
    __shared__ double wd[4];
    __shared__ int wk[4];
    int cnt = *rcnt;
    for (int r = blockIdx.x; r < cnt; r += gridDim.x) {
        int row = rrows[r];
        __syncthreads();
        if (threadIdx.x < DIM) xs[threadIdx.x] = x[row * DIM + threadIdx.x] * xinv[row];
        __syncthreads();
        int wid = threadIdx.x >> 6, lane = threadIdx.x & 63;
        double best = 1e300; int bk = 0x7fffffff;
        double sx = (double)sumx[row];
        float4 xv = ((const float4*)xs)[lane];
        for (int k = wid; k < KCB; k += 4) {
            float4 e4 = ((const float4*)en)[k * (DIM/4) + lane];
            double dp = (double)xv.x * (double)e4.x + (double)xv.y * (double)e4.y
                      + (double)xv.z * (double)e4.z + (double)xv.w * (double)e4.w;
            #pragma unroll
            for (int o = 32; o; o >>= 1) dp += __shfl_xor(dp, o);
            double dist = (sx + (double)sume[k]) - 2.0 * dp;
            if (dist < best) { best = dist; bk = k; }
        }
        if (lane == 0) { wd[wid] = best; wk[wid] = bk; }
        __syncthreads();
        if (threadIdx.x == 0) {
            double b = wd[0]; int k0 = wk[0];
            for (int w = 1; w < 4; w++)
                if (wd[w] < b || (wd[w] == b && wk[w] < k0)) { b = wd[w]; k0 = wk[w]; }
            idx[row] = k0;
        }
    }
}

// gather raw embeddings, straight-through output, loss partials, idx-as-float
__global__ __launch_bounds__(256) void k_gather(const float* __restrict__ x,
                                                const float* __restrict__ emb,
                                                const int* __restrict__ idx,
                                                float* __restrict__ out,
                                                float* __restrict__ lossp) {
    int t = blockIdx.x * 256 + threadIdx.x;
    float ls = 0.f;
    #pragma unroll
    for (int s = 0; s < 4; ++s) {
        int i4 = t + s * 524288;            // NQ/4 = 2097152 = 4*524288
        int n = i4 >> 6, c4 = i4 & 63;
        int id = idx[n];
        float4 f = ((const float4*)x)[i4];
        float4 q = ((const float4*)emb)[id * 64 + c4];
        float dx = q.x - f.x, dy = q.y - f.y, dz = q.z - f.z, dw = q.w - f.w;
        float4 o = make_float4(f.x + dx, f.y + dy, f.z + dz, f.w + dw);
        ((float4*)out)[i4] = o;
        ls += dx*dx + dy*dy + dz*dz + dw*dw;
        if (c4 == 0) out[NQ + 1 + n] = (float)id;
    }
    #pragma unroll
    for (int o = 32; o; o >>= 1) ls += __shfl_xor(ls, o);
    __shared__ float wsum[4];
    int wid = threadIdx.x >> 6, lane = threadIdx.x & 63;
    if (lane == 0) wsum[wid] = ls;
    __syncthreads();
    if (threadIdx.x == 0) lossp[blockIdx.x] = wsum[0] + wsum[1] + wsum[2] + wsum[3];
}

__global__ __launch_bounds__(256) void k_finalize(const float* __restrict__ lossp,
                                                  float* __restrict__ out) {
    double s = 0;
    for (int i = threadIdx.x; i < 2048; i += 256) s += (double)lossp[i];
    #pragma unroll
    for (int o = 32; o; o >>= 1) s += __shfl_xor(s, o);
    __shared__ double wd[4];
    int wid = threadIdx.x >> 6, lane = threadIdx.x & 63;
    if (lane == 0) wd[wid] = s;
    __syncthreads();
    if (threadIdx.x == 0)
        out[NQ] = (float)(0.25 * ((wd[0] + wd[1] + wd[2] + wd[3]) / (double)NQ));
}

extern "C" void kernel_launch(void* const* d_in, const int* in_sizes, int n_in,
                              void* d_out, int out_size, void* d_ws, size_t ws_size,
                              hipStream_t stream) {
    const float* x   = (const float*)d_in[0];
    const float* emb = (const float*)d_in[1];
    char* ws = (char*)d_ws;
    float* en    = (float*)(ws + WS_ENORM);
    float* sume  = (float*)(ws + WS_SUME);
    float* xinv  = (float*)(ws + WS_XINV);
    float* sumx  = (float*)(ws + WS_SUMX);
    int*   idx   = (int*)  (ws + WS_IDX);
    int*   rcnt  = (int*)  (ws + WS_RCNT);
    int*   rrows = (int*)  (ws + WS_RROWS);
    float* lossp = (float*)(ws + WS_LOSSP);
    float* out = (float*)d_out;

    hipLaunchKernelGGL(k_init,    dim3(1),        dim3(64),  0, stream, rcnt);
    hipLaunchKernelGGL(k_norm_x,  dim3(NPTS/4),   dim3(256), 0, stream, x, xinv, sumx);
    hipLaunchKernelGGL(k_norm_e,  dim3(KCB/4),    dim3(256), 0, stream, emb, en, sume);
    hipLaunchKernelGGL(k_phase1,  dim3(NPTS/BM),  dim3(256), 0, stream,
                       x, en, xinv, sumx, sume, idx, rcnt, rrows);
    hipLaunchKernelGGL(k_phase2,  dim3(128),      dim3(256), 0, stream,
                       x, en, xinv, sumx, sume, idx, rcnt, rrows);
    hipLaunchKernelGGL(k_gather,  dim3(2048),     dim3(256), 0, stream,
                       x, emb, idx, out, lossp);
    hipLaunchKernelGGL(k_finalize,dim3(1),        dim3(256), 0, stream, lossp, out);
}

// Round 5
// 1271.341 us; speedup vs baseline: 1.3556x; 1.3556x over previous
//
#include <hip/hip_runtime.h>
#include <math.h>
#include <stdint.h>
#include <limits.h>

#define NPTS 32768
#define DIM  256
#define KCB  4096
#define NQ   (NPTS*DIM)

#define EPSN    1e-12f
#define MARGIN1 6.0e-4f
#define F16MIN  6.103515625e-05f

typedef __attribute__((ext_vector_type(8))) _Float16 f16x8;
typedef __attribute__((ext_vector_type(4))) _Float16 f16x4;
typedef __attribute__((ext_vector_type(4))) float    f32x4;

// ws layout (byte offsets), all regions disjoint, total 2,531,344 B
#define WS_EH0   0u        // KCB*DIM f16 (2,097,152 B) normalized codebook
#define WS_SUME  2097152u  // KCB f32 (16,384 B)
#define WS_EINV  2113536u  // KCB f32 (16,384 B)
#define WS_XINV  2129920u  // NPTS f32 (131,072 B)
#define WS_IDX   2260992u  // NPTS i32 (131,072 B)
#define WS_RC    2392064u  // 1 i32 (pad to 16)
#define WS_RL    2392080u  // NPTS i32 (131,072 B)
#define WS_LOSSP 2523152u  // 2048 f32 (8,192 B)

__device__ inline unsigned fbits(float f){ union{float f;unsigned u;}v; v.f=f; return v.u; }
__device__ inline float bitsf(unsigned u){ union{float f;unsigned u;}v; v.u=u; return v.f; }
__device__ inline _Float16 g16(float v){
    return (fabsf(v) < F16MIN) ? (_Float16)0.0f : (_Float16)v;
}
__device__ inline void gload16(const void* src, void* lds){
    __builtin_amdgcn_global_load_lds((const __attribute__((address_space(1))) void*)src,
                                     (__attribute__((address_space(3))) void*)lds, 16, 0, 0);
}

__global__ void k_init(int* rcnt) {
    if (threadIdx.x == 0) *rcnt = 0;
}

// one wave per input row: inverse norm
__global__ __launch_bounds__(256) void k_norm_x(const float* __restrict__ x,
                                                float* __restrict__ xinv) {
    int w = threadIdx.x >> 6, l = threadIdx.x & 63;
    int row = blockIdx.x * 4 + w;
    float4 v = ((const float4*)x)[row * 64 + l];
    float s = v.x*v.x + v.y*v.y + v.z*v.z + v.w*v.w;
    #pragma unroll
    for (int o = 32; o; o >>= 1) s += __shfl_xor(s, o);
    if (l == 0) xinv[row] = 1.0f / fmaxf(sqrtf(s), EPSN);
}

// one wave per code: f16 normalized row (subnormal-flushed) + fp32 sumsq + invnorm
__global__ __launch_bounds__(256) void k_norm_e(const float* __restrict__ e,
                                                _Float16* __restrict__ eh0,
                                                float* __restrict__ sume,
                                                float* __restrict__ einv) {
    int w = threadIdx.x >> 6, l = threadIdx.x & 63;
    int row = blockIdx.x * 4 + w;
    float4 v = ((const float4*)e)[row * 64 + l];
    float s = v.x*v.x + v.y*v.y + v.z*v.z + v.w*v.w;
    #pragma unroll
    for (int o = 32; o; o >>= 1) s += __shfl_xor(s, o);
    float inv = 1.0f / fmaxf(sqrtf(s), EPSN);
    float4 n = make_float4(v.x*inv, v.y*inv, v.z*inv, v.w*inv);
    f16x4 h0; h0[0]=g16(n.x); h0[1]=g16(n.y); h0[2]=g16(n.z); h0[3]=g16(n.w);
    ((f16x4*)eh0)[row * 64 + l] = h0;
    float s2 = n.x*n.x + n.y*n.y + n.z*n.z + n.w*n.w;
    #pragma unroll
    for (int o = 32; o; o >>= 1) s2 += __shfl_xor(s2, o);
    if (l == 0) { sume[row] = s2; einv[row] = inv; }
}

// tier 1: f16 MFMA distance argmin, top-2 packed keys, flag gap < MARGIN1 (~24 sigma)
__global__ __launch_bounds__(256,1) void k_phase1(
    const float* __restrict__ x, const float* __restrict__ xinv,
    const _Float16* __restrict__ eh0, const float* __restrict__ sume,
    int* __restrict__ idx, int* __restrict__ rcnt, int* __restrict__ rlist)
{
    __shared__ __align__(16) _Float16 Bs[2][64 * DIM];  // 2 x 32 KB
    const int tid = threadIdx.x;
    const int w = tid >> 6, l = tid & 63;
    const int l15 = l & 15, lhi = l >> 4;
    const int rowbase = blockIdx.x * 128 + w * 32;

    // A fragments: lane holds x_norm[row = l15 (+mi*16)][d = dc*32 + lhi*8 + j]
    f16x8 a[2][8];
    #pragma unroll
    for (int mi = 0; mi < 2; mi++) {
        int row = rowbase + mi*16 + l15;
        float xv = xinv[row];
        const float4* xr = (const float4*)(x + row * DIM);
        #pragma unroll
        for (int dc = 0; dc < 8; dc++) {
            float4 f0 = xr[dc*8 + lhi*2];
            float4 f1 = xr[dc*8 + lhi*2 + 1];
            f16x8 av;
            av[0]=g16(f0.x*xv); av[1]=g16(f0.y*xv);
            av[2]=g16(f0.z*xv); av[3]=g16(f0.w*xv);
            av[4]=g16(f1.x*xv); av[5]=g16(f1.y*xv);
            av[6]=g16(f1.z*xv); av[7]=g16(f1.w*xv);
            a[mi][dc] = av;
        }
    }

    uint64_t t0[8], t1[8];
    #pragma unroll
    for (int s = 0; s < 8; s++) { t0[s]=~0ull; t1[s]=~0ull; }

    auto stage = [&](int kt, int buf) {
        const _Float16* gbase = eh0 + kt * 64 * DIM;
        #pragma unroll
        for (int i = 0; i < 8; i++) {
            int dstbyte = (w*512 + i*64 + l) << 4;
            int col = dstbyte >> 9;                  // 512 B per code row
            int off = dstbyte & 511;
            int srcoff = off ^ ((col & 7) << 4);     // inverse-swizzled source
            const void* src = (const void*)((const char*)(gbase + col*DIM) + srcoff);
            void* dst = (void*)((char*)(&Bs[buf][0]) + ((w*512 + i*64) << 4)); // wave-uniform base
            gload16(src, dst);
        }
    };

    stage(0, 0);
    for (int kt = 0; kt < 64; kt++) {
        __syncthreads();                 // drains vmcnt(0): current tile ready
        if (kt < 63) stage(kt + 1, (kt + 1) & 1);
        const int buf = kt & 1;

        float ses[4];
        #pragma unroll
        for (int ni = 0; ni < 4; ni++) ses[ni] = sume[kt*64 + ni*16 + l15];

        f32x4 acc[2][4];
        #pragma unroll
        for (int mi = 0; mi < 2; mi++)
            #pragma unroll
            for (int ni = 0; ni < 4; ni++)
                acc[mi][ni] = (f32x4){0.f, 0.f, 0.f, 0.f};

        #pragma unroll
        for (int dc = 0; dc < 8; dc++) {
            #pragma unroll
            for (int ni = 0; ni < 4; ni++) {
                int col = ni*16 + l15;
                int off = (col*512 + dc*64 + lhi*16) ^ ((col & 7) << 4);
                f16x8 b = *(const f16x8*)((const char*)(&Bs[buf][0]) + off);
                acc[0][ni] = __builtin_amdgcn_mfma_f32_16x16x32_f16(a[0][dc], b, acc[0][ni], 0, 0, 0);
                acc[1][ni] = __builtin_amdgcn_mfma_f32_16x16x32_f16(a[1][dc], b, acc[1][ni], 0, 0, 0);
            }
        }

        #pragma unroll
        for (int ni = 0; ni < 4; ni++) {
            int col = kt*64 + ni*16 + l15;
            #pragma unroll
            for (int mi = 0; mi < 2; mi++) {
                #pragma unroll
                for (int r = 0; r < 4; r++) {
                    float db = 4.0f + ses[ni] - 2.0f * acc[mi][ni][r];   // > 0 always
                    uint64_t key = ((uint64_t)fbits(db) << 32) | (unsigned)col;
                    int s = mi*4 + r;
                    if (key < t1[s]) {
                        if (key < t0[s]) { t1[s] = t0[s]; t0[s] = key; }
                        else t1[s] = key;
                    }
                }
            }
        }
    }

    // merge top-2 across the 16 col-lanes (butterfly over l15 bits)
    #pragma unroll
    for (int s = 0; s < 8; s++) {
        uint64_t a0 = t0[s], a1 = t1[s];
        #pragma unroll
        for (int m = 1; m < 16; m <<= 1) {
            uint64_t b0 = __shfl_xor(a0, m), b1 = __shfl_xor(a1, m);
            uint64_t n0 = a0 < b0 ? a0 : b0;
            uint64_t hi = a0 < b0 ? b0 : a0;
            uint64_t mn = a1 < b1 ? a1 : b1;
            a1 = hi < mn ? hi : mn;
            a0 = n0;
        }
        t0[s] = a0; t1[s] = a1;
    }

    if (l15 == 0) {
        #pragma unroll
        for (int s = 0; s < 8; s++) {
            int mi = s >> 2, r = s & 3;
            int row = rowbase + mi*16 + lhi*4 + r;
            idx[row] = (int)(unsigned)(t0[s] & 0xFFFFFFFFull);
            float d0 = bitsf((unsigned)(t0[s] >> 32));
            float d1 = bitsf((unsigned)(t1[s] >> 32));
            if (d1 - d0 < MARGIN1) {
                int p = atomicAdd(rcnt, 1);
                if (p < NPTS) rlist[p] = row;
            }
        }
    }
}

// tier 2: exact f64 full-K rescore for flagged rows (round-1-verified structure)
__global__ __launch_bounds__(256) void k_exact(
    const float* __restrict__ x, const float* __restrict__ emb,
    const float* __restrict__ xinv, const float* __restrict__ einv,
    const float* __restrict__ sume,
    const int* __restrict__ rcnt, const int* __restrict__ rlist,
    int* __restrict__ idx)
{
    __shared__ __align__(16) float xs[DIM];
    __shared__ double wd[4];
    __shared__ int wk[4];
    int cnt = *rcnt; if (cnt > NPTS) cnt = NPTS;
    for (int r = blockIdx.x; r < cnt; r += gridDim.x) {
        int row = rlist[r];
        __syncthreads();
        if (threadIdx.x < DIM) xs[threadIdx.x] = x[row * DIM + threadIdx.x] * xinv[row];
        __syncthreads();
        int wid = threadIdx.x >> 6, lane = threadIdx.x & 63;
        double best = 1e300; int bk = INT_MAX;
        float4 xv = ((const float4*)xs)[lane];
        for (int k = wid; k < KCB; k += 4) {
            float ev = einv[k];
            float4 e4 = ((const float4*)emb)[k * 64 + lane];
            double dp = (double)xv.x * (double)(e4.x*ev) + (double)xv.y * (double)(e4.y*ev)
                      + (double)xv.z * (double)(e4.z*ev) + (double)xv.w * (double)(e4.w*ev);
            #pragma unroll
            for (int o = 32; o; o >>= 1) dp += __shfl_xor(dp, o);
            double dist = (double)sume[k] - 2.0 * dp;
            if (dist < best || (dist == best && k < bk)) { best = dist; bk = k; }
        }
        if (lane == 0) { wd[wid] = best; wk[wid] = bk; }
        __syncthreads();
        if (threadIdx.x == 0) {
            double b = wd[0]; int k0 = wk[0];
            for (int ww = 1; ww < 4; ww++)
                if (wd[ww] < b || (wd[ww] == b && wk[ww] < k0)) { b = wd[ww]; k0 = wk[ww]; }
            idx[row] = k0;
        }
    }
}

// gather raw embeddings, straight-through output, loss partials, idx-as-float
__global__ __launch_bounds__(256) void k_gather(const float* __restrict__ x,
                                                const float* __restrict__ emb,
                                                const int* __restrict__ idx,
                                                float* __restrict__ out,
                                                float* __restrict__ lossp) {
    int t = blockIdx.x * 256 + threadIdx.x;
    float ls = 0.f;
    #pragma unroll
    for (int s = 0; s < 4; ++s) {
        int i4 = t + s * 524288;
        int n = i4 >> 6, c4 = i4 & 63;
        int id = idx[n];
        float4 f = ((const float4*)x)[i4];
        float4 q = ((const float4*)emb)[id * 64 + c4];
        float dx = q.x - f.x, dy = q.y - f.y, dz = q.z - f.z, dw = q.w - f.w;
        float4 o = make_float4(f.x + dx, f.y + dy, f.z + dz, f.w + dw);
        ((float4*)out)[i4] = o;
        ls += dx*dx + dy*dy + dz*dz + dw*dw;
        if (c4 == 0) out[NQ + 1 + n] = (float)id;
    }
    #pragma unroll
    for (int o = 32; o; o >>= 1) ls += __shfl_xor(ls, o);
    __shared__ float wsum[4];
    int wid = threadIdx.x >> 6, lane = threadIdx.x & 63;
    if (lane == 0) wsum[wid] = ls;
    __syncthreads();
    if (threadIdx.x == 0) lossp[blockIdx.x] = wsum[0] + wsum[1] + wsum[2] + wsum[3];
}

__global__ __launch_bounds__(256) void k_finalize(const float* __restrict__ lossp,
                                                  float* __restrict__ out) {
    double s = 0;
    for (int i = threadIdx.x; i < 2048; i += 256) s += (double)lossp[i];
    #pragma unroll
    for (int o = 32; o; o >>= 1) s += __shfl_xor(s, o);
    __shared__ double wd[4];
    int wid = threadIdx.x >> 6, lane = threadIdx.x & 63;
    if (lane == 0) wd[wid] = s;
    __syncthreads();
    if (threadIdx.x == 0)
        out[NQ] = (float)(0.25 * ((wd[0] + wd[1] + wd[2] + wd[3]) / (double)NQ));
}

extern "C" void kernel_launch(void* const* d_in, const int* in_sizes, int n_in,
                              void* d_out, int out_size, void* d_ws, size_t ws_size,
                              hipStream_t stream) {
    const float* x   = (const float*)d_in[0];
    const float* emb = (const float*)d_in[1];
    char* ws = (char*)d_ws;
    _Float16* eh0 = (_Float16*)(ws + WS_EH0);
    float* sume  = (float*)(ws + WS_SUME);
    float* einv  = (float*)(ws + WS_EINV);
    float* xinv  = (float*)(ws + WS_XINV);
    int*   idx   = (int*)  (ws + WS_IDX);
    int*   rcnt  = (int*)  (ws + WS_RC);
    int*   rlist = (int*)  (ws + WS_RL);
    float* lossp = (float*)(ws + WS_LOSSP);
    float* out = (float*)d_out;

    hipLaunchKernelGGL(k_init,    dim3(1),        dim3(64),  0, stream, rcnt);
    hipLaunchKernelGGL(k_norm_x,  dim3(NPTS/4),   dim3(256), 0, stream, x, xinv);
    hipLaunchKernelGGL(k_norm_e,  dim3(KCB/4),    dim3(256), 0, stream, emb, eh0, sume, einv);
    hipLaunchKernelGGL(k_phase1,  dim3(NPTS/128), dim3(256), 0, stream,
                       x, xinv, eh0, sume, idx, rcnt, rlist);
    hipLaunchKernelGGL(k_exact,   dim3(512),      dim3(256), 0, stream,
                       x, emb, xinv, einv, sume, rcnt, rlist, idx);
    hipLaunchKernelGGL(k_gather,  dim3(2048),     dim3(256), 0, stream,
                       x, emb, idx, out, lossp);
    hipLaunchKernelGGL(k_finalize,dim3(1),        dim3(256), 0, stream, lossp, out);
}

// Round 6
// 612.678 us; speedup vs baseline: 2.8129x; 2.0751x over previous
//
#include <hip/hip_runtime.h>
#include <math.h>
#include <stdint.h>
#include <limits.h>

#define NPTS 32768
#define DIM  256
#define KCB  4096
#define NQ   (NPTS*DIM)

#define EPSN    1e-12f
#define MARGIN1 6.0e-4f
#define F16MIN  6.103515625e-05f

typedef __attribute__((ext_vector_type(8))) _Float16 f16x8;
typedef __attribute__((ext_vector_type(4))) _Float16 f16x4;
typedef __attribute__((ext_vector_type(4))) float    f32x4;

// ws layout (byte offsets), all regions disjoint, total 2,531,344 B
#define WS_EH0   0u        // KCB*DIM f16 (2,097,152 B) normalized codebook
#define WS_SUME  2097152u  // KCB f32 (16,384 B)
#define WS_EINV  2113536u  // KCB f32 (16,384 B)
#define WS_XINV  2129920u  // NPTS f32 (131,072 B)
#define WS_IDX   2260992u  // NPTS i32 (131,072 B)
#define WS_RC    2392064u  // 1 i32 (pad to 16)
#define WS_RL    2392080u  // NPTS i32 (131,072 B)
#define WS_LOSSP 2523152u  // 2048 f32 (8,192 B)

__device__ inline unsigned fbits(float f){ union{float f;unsigned u;}v; v.f=f; return v.u; }
__device__ inline float bitsf(unsigned u){ union{float f;unsigned u;}v; v.u=u; return v.f; }
__device__ inline _Float16 g16(float v){
    return (fabsf(v) < F16MIN) ? (_Float16)0.0f : (_Float16)v;
}
__device__ inline void gload16(const void* src, void* lds){
    __builtin_amdgcn_global_load_lds((const __attribute__((address_space(1))) void*)src,
                                     (__attribute__((address_space(3))) void*)lds, 16, 0, 0);
}

__global__ void k_init(int* rcnt) {
    if (threadIdx.x == 0) *rcnt = 0;
}

// one wave per input row: inverse norm
__global__ __launch_bounds__(256) void k_norm_x(const float* __restrict__ x,
                                                float* __restrict__ xinv) {
    int w = threadIdx.x >> 6, l = threadIdx.x & 63;
    int row = blockIdx.x * 4 + w;
    float4 v = ((const float4*)x)[row * 64 + l];
    float s = v.x*v.x + v.y*v.y + v.z*v.z + v.w*v.w;
    #pragma unroll
    for (int o = 32; o; o >>= 1) s += __shfl_xor(s, o);
    if (l == 0) xinv[row] = 1.0f / fmaxf(sqrtf(s), EPSN);
}

// one wave per code: f16 normalized row (subnormal-flushed) + fp32 sumsq + invnorm
__global__ __launch_bounds__(256) void k_norm_e(const float* __restrict__ e,
                                                _Float16* __restrict__ eh0,
                                                float* __restrict__ sume,
                                                float* __restrict__ einv) {
    int w = threadIdx.x >> 6, l = threadIdx.x & 63;
    int row = blockIdx.x * 4 + w;
    float4 v = ((const float4*)e)[row * 64 + l];
    float s = v.x*v.x + v.y*v.y + v.z*v.z + v.w*v.w;
    #pragma unroll
    for (int o = 32; o; o >>= 1) s += __shfl_xor(s, o);
    float inv = 1.0f / fmaxf(sqrtf(s), EPSN);
    float4 n = make_float4(v.x*inv, v.y*inv, v.z*inv, v.w*inv);
    f16x4 h0; h0[0]=g16(n.x); h0[1]=g16(n.y); h0[2]=g16(n.z); h0[3]=g16(n.w);
    ((f16x4*)eh0)[row * 64 + l] = h0;
    float s2 = n.x*n.x + n.y*n.y + n.z*n.z + n.w*n.w;
    #pragma unroll
    for (int o = 32; o; o >>= 1) s2 += __shfl_xor(s2, o);
    if (l == 0) { sume[row] = s2; einv[row] = inv; }
}

// tier 1: f16 MFMA distance argmin, top-2 packed keys, flag gap < MARGIN1 (~8.5 sigma)
__global__ __launch_bounds__(256,1) void k_phase1(
    const float* __restrict__ x, const float* __restrict__ xinv,
    const _Float16* __restrict__ eh0, const float* __restrict__ sume,
    int* __restrict__ idx, int* __restrict__ rcnt, int* __restrict__ rlist)
{
    __shared__ __align__(16) _Float16 Bs[2][64 * DIM];  // 2 x 32 KB
    const int tid = threadIdx.x;
    const int w = tid >> 6, l = tid & 63;
    const int l15 = l & 15, lhi = l >> 4;
    const int rowbase = blockIdx.x * 128 + w * 32;

    // A fragments: lane holds x_norm[row = l15 (+mi*16)][d = dc*32 + lhi*8 + j]
    f16x8 a[2][8];
    #pragma unroll
    for (int mi = 0; mi < 2; mi++) {
        int row = rowbase + mi*16 + l15;
        float xv = xinv[row];
        const float4* xr = (const float4*)(x + row * DIM);
        #pragma unroll
        for (int dc = 0; dc < 8; dc++) {
            float4 f0 = xr[dc*8 + lhi*2];
            float4 f1 = xr[dc*8 + lhi*2 + 1];
            f16x8 av;
            av[0]=g16(f0.x*xv); av[1]=g16(f0.y*xv);
            av[2]=g16(f0.z*xv); av[3]=g16(f0.w*xv);
            av[4]=g16(f1.x*xv); av[5]=g16(f1.y*xv);
            av[6]=g16(f1.z*xv); av[7]=g16(f1.w*xv);
            a[mi][dc] = av;
        }
    }

    uint64_t t0[8], t1[8];
    #pragma unroll
    for (int s = 0; s < 8; s++) { t0[s]=~0ull; t1[s]=~0ull; }

    auto stage = [&](int kt, int buf) {
        const _Float16* gbase = eh0 + kt * 64 * DIM;
        #pragma unroll
        for (int i = 0; i < 8; i++) {
            int dstbyte = (w*512 + i*64 + l) << 4;
            int col = dstbyte >> 9;                  // 512 B per code row
            int off = dstbyte & 511;
            int srcoff = off ^ ((col & 7) << 4);     // inverse-swizzled source
            const void* src = (const void*)((const char*)(gbase + col*DIM) + srcoff);
            void* dst = (void*)((char*)(&Bs[buf][0]) + ((w*512 + i*64) << 4)); // wave-uniform base
            gload16(src, dst);
        }
    };

    stage(0, 0);
    for (int kt = 0; kt < 64; kt++) {
        __syncthreads();                 // drains vmcnt(0): current tile ready
        if (kt < 63) stage(kt + 1, (kt + 1) & 1);
        const int buf = kt & 1;

        float ses[4];
        #pragma unroll
        for (int ni = 0; ni < 4; ni++) ses[ni] = sume[kt*64 + ni*16 + l15];

        f32x4 acc[2][4];
        #pragma unroll
        for (int mi = 0; mi < 2; mi++)
            #pragma unroll
            for (int ni = 0; ni < 4; ni++)
                acc[mi][ni] = (f32x4){0.f, 0.f, 0.f, 0.f};

        #pragma unroll
        for (int dc = 0; dc < 8; dc++) {
            #pragma unroll
            for (int ni = 0; ni < 4; ni++) {
                int col = ni*16 + l15;
                int off = (col*512 + dc*64 + lhi*16) ^ ((col & 7) << 4);
                f16x8 b = *(const f16x8*)((const char*)(&Bs[buf][0]) + off);
                acc[0][ni] = __builtin_amdgcn_mfma_f32_16x16x32_f16(a[0][dc], b, acc[0][ni], 0, 0, 0);
                acc[1][ni] = __builtin_amdgcn_mfma_f32_16x16x32_f16(a[1][dc], b, acc[1][ni], 0, 0, 0);
            }
        }

        #pragma unroll
        for (int ni = 0; ni < 4; ni++) {
            int col = kt*64 + ni*16 + l15;
            #pragma unroll
            for (int mi = 0; mi < 2; mi++) {
                #pragma unroll
                for (int r = 0; r < 4; r++) {
                    float db = 4.0f + ses[ni] - 2.0f * acc[mi][ni][r];   // > 0 always
                    uint64_t key = ((uint64_t)fbits(db) << 32) | (unsigned)col;
                    int s = mi*4 + r;
                    if (key < t1[s]) {
                        if (key < t0[s]) { t1[s] = t0[s]; t0[s] = key; }
                        else t1[s] = key;
                    }
                }
            }
        }
    }

    // merge top-2 across the 16 col-lanes (butterfly over l15 bits)
    #pragma unroll
    for (int s = 0; s < 8; s++) {
        uint64_t a0 = t0[s], a1 = t1[s];
        #pragma unroll
        for (int m = 1; m < 16; m <<= 1) {
            uint64_t b0 = __shfl_xor(a0, m), b1 = __shfl_xor(a1, m);
            uint64_t n0 = a0 < b0 ? a0 : b0;
            uint64_t hi = a0 < b0 ? b0 : a0;
            uint64_t mn = a1 < b1 ? a1 : b1;
            a1 = hi < mn ? hi : mn;
            a0 = n0;
        }
        t0[s] = a0; t1[s] = a1;
    }

    if (l15 == 0) {
        #pragma unroll
        for (int s = 0; s < 8; s++) {
            int mi = s >> 2, r = s & 3;
            int row = rowbase + mi*16 + lhi*4 + r;
            idx[row] = (int)(unsigned)(t0[s] & 0xFFFFFFFFull);
            float d0 = bitsf((unsigned)(t0[s] >> 32));
            float d1 = bitsf((unsigned)(t1[s] >> 32));
            if (d1 - d0 < MARGIN1) {
                int p = atomicAdd(rcnt, 1);
                if (p < NPTS) rlist[p] = row;
            }
        }
    }
}

// tier 2: exact f64 full-K rescore for flagged rows.
// Block-per-row: thread t owns codes {t + 256c}, serial f64 dot over D with
// 4 independent partials (ILP); x-row broadcast from LDS; LDS argmin tree.
__global__ __launch_bounds__(256) void k_exact(
    const float* __restrict__ x, const float* __restrict__ emb,
    const float* __restrict__ xinv, const float* __restrict__ einv,
    const float* __restrict__ sume,
    const int* __restrict__ rcnt, const int* __restrict__ rlist,
    int* __restrict__ idx)
{
    __shared__ __align__(16) float xs[DIM];
    __shared__ double sd[256];
    __shared__ int si[256];
    int tid = threadIdx.x;
    int cnt = *rcnt; if (cnt > NPTS) cnt = NPTS; if (cnt <= 0) return;
    for (int r = blockIdx.x; r < cnt; r += gridDim.x) {
        int row = rlist[r];
        __syncthreads();
        xs[tid] = x[row * DIM + tid] * xinv[row];
        __syncthreads();
        double best = 1e300; int bk = INT_MAX;
        const float4* x4s = (const float4*)xs;
        for (int c = 0; c < 16; c++) {
            int k = tid + c * 256;
            float ev = einv[k];
            const float4* e4 = (const float4*)(emb + k * DIM);
            double d0 = 0, d1 = 0, d2 = 0, d3 = 0;
            #pragma unroll 8
            for (int i = 0; i < 64; i++) {
                float4 ef = e4[i]; float4 xf = x4s[i];
                d0 += (double)xf.x * (double)(ef.x * ev);
                d1 += (double)xf.y * (double)(ef.y * ev);
                d2 += (double)xf.z * (double)(ef.z * ev);
                d3 += (double)xf.w * (double)(ef.w * ev);
            }
            double dist = (double)sume[k] - 2.0 * ((d0 + d1) + (d2 + d3));
            if (dist < best || (dist == best && k < bk)) { best = dist; bk = k; }
        }
        sd[tid] = best; si[tid] = bk;
        __syncthreads();
        for (int s = 128; s > 0; s >>= 1) {
            if (tid < s) {
                if (sd[tid+s] < sd[tid] || (sd[tid+s] == sd[tid] && si[tid+s] < si[tid])) {
                    sd[tid] = sd[tid+s]; si[tid] = si[tid+s];
                }
            }
            __syncthreads();
        }
        if (tid == 0) idx[row] = si[0];
        __syncthreads();
    }
}

// gather raw embeddings, straight-through output, loss partials, idx-as-float
__global__ __launch_bounds__(256) void k_gather(const float* __restrict__ x,
                                                const float* __restrict__ emb,
                                                const int* __restrict__ idx,
                                                float* __restrict__ out,
                                                float* __restrict__ lossp) {
    int t = blockIdx.x * 256 + threadIdx.x;
    float ls = 0.f;
    #pragma unroll
    for (int s = 0; s < 4; ++s) {
        int i4 = t + s * 524288;
        int n = i4 >> 6, c4 = i4 & 63;
        int id = idx[n];
        float4 f = ((const float4*)x)[i4];
        float4 q = ((const float4*)emb)[id * 64 + c4];
        float dx = q.x - f.x, dy = q.y - f.y, dz = q.z - f.z, dw = q.w - f.w;
        float4 o = make_float4(f.x + dx, f.y + dy, f.z + dz, f.w + dw);
        ((float4*)out)[i4] = o;
        ls += dx*dx + dy*dy + dz*dz + dw*dw;
        if (c4 == 0) out[NQ + 1 + n] = (float)id;
    }
    #pragma unroll
    for (int o = 32; o; o >>= 1) ls += __shfl_xor(ls, o);
    __shared__ float wsum[4];
    int wid = threadIdx.x >> 6, lane = threadIdx.x & 63;
    if (lane == 0) wsum[wid] = ls;
    __syncthreads();
    if (threadIdx.x == 0) lossp[blockIdx.x] = wsum[0] + wsum[1] + wsum[2] + wsum[3];
}

__global__ __launch_bounds__(256) void k_finalize(const float* __restrict__ lossp,
                                                  float* __restrict__ out) {
    double s = 0;
    for (int i = threadIdx.x; i < 2048; i += 256) s += (double)lossp[i];
    #pragma unroll
    for (int o = 32; o; o >>= 1) s += __shfl_xor(s, o);
    __shared__ double wd[4];
    int wid = threadIdx.x >> 6, lane = threadIdx.x & 63;
    if (lane == 0) wd[wid] = s;
    __syncthreads();
    if (threadIdx.x == 0)
        out[NQ] = (float)(0.25 * ((wd[0] + wd[1] + wd[2] + wd[3]) / (double)NQ));
}

extern "C" void kernel_launch(void* const* d_in, const int* in_sizes, int n_in,
                              void* d_out, int out_size, void* d_ws, size_t ws_size,
                              hipStream_t stream) {
    const float* x   = (const float*)d_in[0];
    const float* emb = (const float*)d_in[1];
    char* ws = (char*)d_ws;
    _Float16* eh0 = (_Float16*)(ws + WS_EH0);
    float* sume  = (float*)(ws + WS_SUME);
    float* einv  = (float*)(ws + WS_EINV);
    float* xinv  = (float*)(ws + WS_XINV);
    int*   idx   = (int*)  (ws + WS_IDX);
    int*   rcnt  = (int*)  (ws + WS_RC);
    int*   rlist = (int*)  (ws + WS_RL);
    float* lossp = (float*)(ws + WS_LOSSP);
    float* out = (float*)d_out;

    hipLaunchKernelGGL(k_init,    dim3(1),        dim3(64),  0, stream, rcnt);
    hipLaunchKernelGGL(k_norm_x,  dim3(NPTS/4),   dim3(256), 0, stream, x, xinv);
    hipLaunchKernelGGL(k_norm_e,  dim3(KCB/4),    dim3(256), 0, stream, emb, eh0, sume, einv);
    hipLaunchKernelGGL(k_phase1,  dim3(NPTS/128), dim3(256), 0, stream,
                       x, xinv, eh0, sume, idx, rcnt, rlist);
    hipLaunchKernelGGL(k_exact,   dim3(1024),     dim3(256), 0, stream,
                       x, emb, xinv, einv, sume, rcnt, rlist, idx);
    hipLaunchKernelGGL(k_gather,  dim3(2048),     dim3(256), 0, stream,
                       x, emb, idx, out, lossp);
    hipLaunchKernelGGL(k_finalize,dim3(1),        dim3(256), 0, stream, lossp, out);
}